// Round 1
// baseline (773.633 us; speedup 1.0000x reference)
//
#include <hip/hip_runtime.h>

#define LEN 256
#define ROWS_PER_BLOCK 4

__device__ __forceinline__ float wave_max(float v) {
#pragma unroll
    for (int m = 32; m >= 1; m >>= 1) v = fmaxf(v, __shfl_xor(v, m, 64));
    return v;
}

__device__ __forceinline__ float wave_sum(float v) {
#pragma unroll
    for (int m = 32; m >= 1; m >>= 1) v += __shfl_xor(v, m, 64);
    return v;
}

// FWHT-256 across one wave: lane holds elements [4*lane .. 4*lane+3] in r[0..3].
// FWHT stage order is free (tensor product of 2x2 H across the 8 index bits).
__device__ __forceinline__ void fwht256(float r[4], int lane) {
    // index bits 0,1 (in-lane)
    float t0 = r[0] + r[1], t1 = r[0] - r[1];
    float t2 = r[2] + r[3], t3 = r[2] - r[3];
    r[0] = t0 + t2; r[1] = t1 + t3;
    r[2] = t0 - t2; r[3] = t1 - t3;
    // index bits 2..7 (cross-lane, xor masks 1..32)
#pragma unroll
    for (int m = 1; m <= 32; m <<= 1) {
        float s = (lane & m) ? -1.0f : 1.0f;
#pragma unroll
        for (int j = 0; j < 4; ++j) {
            float other = __shfl_xor(r[j], m, 64);
            r[j] = fmaf(s, r[j], other);  // lower: self+other ; upper: other-self
        }
    }
}

__device__ __forceinline__ void log_softmax_store(const float v[4],
                                                  float* __restrict__ row_out,
                                                  int lane) {
    float mx = wave_max(fmaxf(fmaxf(v[0], v[1]), fmaxf(v[2], v[3])));
    float s = __expf(v[0] - mx) + __expf(v[1] - mx) +
              __expf(v[2] - mx) + __expf(v[3] - mx);
    s = wave_sum(s);
    float lse = mx + __logf(s);
    float4 o = make_float4(v[0] - lse, v[1] - lse, v[2] - lse, v[3] - lse);
    ((float4*)row_out)[lane] = o;
}

__global__ __launch_bounds__(256) void group_recombine_kernel(
        const float* __restrict__ b0, const float* __restrict__ b1,
        const float* __restrict__ mk, float* __restrict__ out, int rows) {
    const int wave = threadIdx.x >> 6;
    const int lane = threadIdx.x & 63;
    const int row = blockIdx.x * ROWS_PER_BLOCK + wave;
    if (row >= rows) return;

    const size_t base = (size_t)row * LEN;
    const size_t stride = (size_t)rows * LEN;

    // ---- share 0 ----
    float4 v = ((const float4*)(b0 + base))[lane];
    float a[4] = {v.x, v.y, v.z, v.w};
    float w0[4] = {a[0], a[1], a[2], a[3]};
    fwht256(w0, lane);
    log_softmax_store(a, out + base, lane);

    // ---- share 1 ----
    v = ((const float4*)(b1 + base))[lane];
    float b[4] = {v.x, v.y, v.z, v.w};
    float w1[4] = {b[0], b[1], b[2], b[3]};
    fwht256(w1, lane);
    log_softmax_store(b, out + stride + base, lane);

    // ---- share 2 ----
    v = ((const float4*)(mk + base))[lane];
    float c[4] = {v.x, v.y, v.z, v.w};
    float w2[4] = {c[0], c[1], c[2], c[3]};
    fwht256(w2, lane);
    log_softmax_store(c, out + 2 * stride + base, lane);

    // ---- WH-domain product, inverse transform, scale 1/256 ----
    float pr[4];
#pragma unroll
    for (int j = 0; j < 4; ++j) pr[j] = w0[j] * w1[j] * w2[j];
    fwht256(pr, lane);
#pragma unroll
    for (int j = 0; j < 4; ++j) pr[j] *= (1.0f / 256.0f);
    log_softmax_store(pr, out + 3 * stride + base, lane);
}

extern "C" void kernel_launch(void* const* d_in, const int* in_sizes, int n_in,
                              void* d_out, int out_size, void* d_ws, size_t ws_size,
                              hipStream_t stream) {
    const float* b0 = (const float*)d_in[0];
    const float* b1 = (const float*)d_in[1];
    const float* mk = (const float*)d_in[2];
    float* out = (float*)d_out;
    const int rows = in_sizes[0] / LEN;  // 131072
    dim3 grid((rows + ROWS_PER_BLOCK - 1) / ROWS_PER_BLOCK);
    dim3 block(64 * ROWS_PER_BLOCK);
    group_recombine_kernel<<<grid, block, 0, stream>>>(b0, b1, mk, out, rows);
}